// Round 1
// baseline (2246.564 us; speedup 1.0000x reference)
//
#include <hip/hip_runtime.h>

#define N_NODES 100000
#define N_EDGES 1250000
#define IN_C 64
#define HID_C 128
#define OUT_C 64

// ---------- edge dtype detection (int64 vs int32 on device) ----------
// If edges are int64 little-endian, every odd u32 word (hi word) is 0 since
// ids < 2^31. If int32, odd words are random node ids (all-zero prob ~0).
__global__ void detect_i64_kernel(const unsigned int* __restrict__ e, int* __restrict__ flag) {
    unsigned v = e[2 * threadIdx.x + 1];
    unsigned long long b = __ballot(v != 0u);
    if (threadIdx.x == 0) flag[0] = (b == 0ull) ? 1 : 0;
}

__global__ void hist_kernel(const unsigned int* __restrict__ e, const int* __restrict__ flag,
                            int* __restrict__ deg) {
    const bool i64 = flag[0] != 0;
    for (int i = blockIdx.x * blockDim.x + threadIdx.x; i < N_EDGES;
         i += gridDim.x * blockDim.x) {
        int d = i64 ? (int)e[2 * (N_EDGES + i)] : (int)e[N_EDGES + i];
        atomicAdd(&deg[d], 1);
    }
}

__global__ __launch_bounds__(1024) void scan_block_kernel(const int* __restrict__ deg,
                                                          int* __restrict__ excl,
                                                          int* __restrict__ bsum) {
    __shared__ int s[1024];
    int tid = threadIdx.x;
    int i = blockIdx.x * 1024 + tid;
    int v = (i < N_NODES) ? deg[i] : 0;
    s[tid] = v;
    __syncthreads();
    for (int off = 1; off < 1024; off <<= 1) {
        int t = (tid >= off) ? s[tid - off] : 0;
        __syncthreads();
        s[tid] += t;
        __syncthreads();
    }
    if (i < N_NODES) excl[i] = s[tid] - v;
    if (tid == 1023) bsum[blockIdx.x] = s[1023];
}

__global__ void scan_top_kernel(int* __restrict__ bsum, int nb) {
    __shared__ int s[128];
    int tid = threadIdx.x;
    int v = (tid < nb) ? bsum[tid] : 0;
    s[tid] = v;
    __syncthreads();
    for (int off = 1; off < 128; off <<= 1) {
        int t = (tid >= off) ? s[tid - off] : 0;
        __syncthreads();
        s[tid] += t;
        __syncthreads();
    }
    if (tid < nb) bsum[tid] = s[tid] - v;
}

__global__ void add_off_kernel(int* __restrict__ excl, const int* __restrict__ bsum,
                               int* __restrict__ cursor) {
    for (int i = blockIdx.x * blockDim.x + threadIdx.x; i < N_NODES;
         i += gridDim.x * blockDim.x) {
        int v = excl[i] + bsum[i >> 10];
        excl[i] = v;
        cursor[i] = v;
        if (i == 0) excl[N_NODES] = N_EDGES;
    }
}

__global__ void fill_kernel(const unsigned int* __restrict__ e, const int* __restrict__ flag,
                            int* __restrict__ cursor, int* __restrict__ csr_src) {
    const bool i64 = flag[0] != 0;
    for (int i = blockIdx.x * blockDim.x + threadIdx.x; i < N_EDGES;
         i += gridDim.x * blockDim.x) {
        int sv = i64 ? (int)e[2 * i] : (int)e[i];
        int dv = i64 ? (int)e[2 * (N_EDGES + i)] : (int)e[N_EDGES + i];
        int pos = atomicAdd(&cursor[dv], 1);
        csr_src[pos] = sv;
    }
}

// ---------- layer 0: h0 = relu(mean(x_nbr) @ Wl0 + b + x @ Wr0) ----------
// block = 256 threads = 2 nodes x 128 out-channels; 64 nodes per block.
__global__ __launch_bounds__(256) void layer0_kernel(
    const float* __restrict__ x, const int* __restrict__ off, const int* __restrict__ csr_src,
    const float* __restrict__ Wl, const float* __restrict__ Wr, const float* __restrict__ bl,
    float* __restrict__ h0) {
    __shared__ float wl_s[IN_C * HID_C];   // 32 KB
    __shared__ float wr_s[IN_C * HID_C];   // 32 KB
    __shared__ float b_s[HID_C];
    __shared__ float mean_s[2][IN_C];
    __shared__ float xs_s[2][IN_C];

    {
        const float4* wl4 = (const float4*)Wl;
        const float4* wr4 = (const float4*)Wr;
        float4* dl = (float4*)wl_s;
        float4* dr = (float4*)wr_s;
        for (int i = threadIdx.x; i < IN_C * HID_C / 4; i += 256) {
            dl[i] = wl4[i];
            dr[i] = wr4[i];
        }
        if (threadIdx.x < HID_C) b_s[threadIdx.x] = bl[threadIdx.x];
    }
    __syncthreads();

    const int half = threadIdx.x >> 7;
    const int lane = threadIdx.x & 127;
    const int base = blockIdx.x * 64;

    for (int it = 0; it < 32; ++it) {
        int node = base + it * 2 + half;
        bool valid = node < N_NODES;
        if (valid && lane < IN_C) {
            int beg = off[node], end = off[node + 1];
            float s = 0.f;
            int ee = beg;
            for (; ee + 4 <= end; ee += 4) {
                int s0 = csr_src[ee], s1 = csr_src[ee + 1];
                int s2 = csr_src[ee + 2], s3 = csr_src[ee + 3];
                float a = x[s0 * IN_C + lane];
                float b = x[s1 * IN_C + lane];
                float c = x[s2 * IN_C + lane];
                float d = x[s3 * IN_C + lane];
                s += (a + b) + (c + d);
            }
            for (; ee < end; ++ee) s += x[csr_src[ee] * IN_C + lane];
            float invd = (end > beg) ? 1.f / (float)(end - beg) : 1.f;
            mean_s[half][lane] = s * invd;
            xs_s[half][lane] = x[node * IN_C + lane];
        }
        __syncthreads();
        if (valid) {
            float acc = b_s[lane];
            const float* m = mean_s[half];
            const float* xv = xs_s[half];
#pragma unroll 16
            for (int k = 0; k < IN_C; ++k)
                acc += m[k] * wl_s[k * HID_C + lane] + xv[k] * wr_s[k * HID_C + lane];
            h0[node * HID_C + lane] = fmaxf(acc, 0.f);
        }
        __syncthreads();
    }
}

// ---- layer 1 + out: out = (relu(mean(h0_nbr)@Wl1 + b1 + h0@Wr1)) @ Wout + bout ----
// block = 256 threads = 2 nodes x 128; Wl1/Wr1 in LDS (128 KB), Wout via L1.
__global__ __launch_bounds__(256) void layer1_kernel(
    const float* __restrict__ h0, const int* __restrict__ off, const int* __restrict__ csr_src,
    const float* __restrict__ Wl, const float* __restrict__ Wr, const float* __restrict__ bl,
    const float* __restrict__ Wout, const float* __restrict__ bout, float* __restrict__ out) {
    __shared__ float wl_s[HID_C * HID_C];  // 64 KB
    __shared__ float wr_s[HID_C * HID_C];  // 64 KB
    __shared__ float b_s[HID_C];
    __shared__ float bo_s[OUT_C];
    __shared__ float mean_s[2][HID_C];
    __shared__ float hs_s[2][HID_C];
    __shared__ float h1_s[2][HID_C];
    __shared__ float part_s[2][HID_C];

    {
        const float4* wl4 = (const float4*)Wl;
        const float4* wr4 = (const float4*)Wr;
        float4* dl = (float4*)wl_s;
        float4* dr = (float4*)wr_s;
        for (int i = threadIdx.x; i < HID_C * HID_C / 4; i += 256) {
            dl[i] = wl4[i];
            dr[i] = wr4[i];
        }
        if (threadIdx.x < HID_C) b_s[threadIdx.x] = bl[threadIdx.x];
        if (threadIdx.x < OUT_C) bo_s[threadIdx.x] = bout[threadIdx.x];
    }
    __syncthreads();

    const int half = threadIdx.x >> 7;
    const int lane = threadIdx.x & 127;
    const int base = blockIdx.x * 64;

    for (int it = 0; it < 32; ++it) {
        int node = base + it * 2 + half;
        bool valid = node < N_NODES;
        if (valid) {
            int beg = off[node], end = off[node + 1];
            float s = 0.f;
            int ee = beg;
            for (; ee + 4 <= end; ee += 4) {
                int s0 = csr_src[ee], s1 = csr_src[ee + 1];
                int s2 = csr_src[ee + 2], s3 = csr_src[ee + 3];
                float a = h0[s0 * HID_C + lane];
                float b = h0[s1 * HID_C + lane];
                float c = h0[s2 * HID_C + lane];
                float d = h0[s3 * HID_C + lane];
                s += (a + b) + (c + d);
            }
            for (; ee < end; ++ee) s += h0[csr_src[ee] * HID_C + lane];
            float invd = (end > beg) ? 1.f / (float)(end - beg) : 1.f;
            mean_s[half][lane] = s * invd;
            hs_s[half][lane] = h0[node * HID_C + lane];
        }
        __syncthreads();
        if (valid) {
            float acc = b_s[lane];
            const float* m = mean_s[half];
            const float* hv = hs_s[half];
#pragma unroll 8
            for (int k = 0; k < HID_C; ++k)
                acc += m[k] * wl_s[k * HID_C + lane] + hv[k] * wr_s[k * HID_C + lane];
            h1_s[half][lane] = fmaxf(acc, 0.f);
        }
        __syncthreads();
        if (valid) {
            int oc = lane & 63;
            int kh = lane >> 6;  // split k-range over two thread groups
            const float* hv = h1_s[half] + kh * 64;
            const float* wo = Wout + kh * 64 * OUT_C + oc;
            float o = 0.f;
#pragma unroll 8
            for (int k = 0; k < 64; ++k) o += hv[k] * wo[k * OUT_C];
            part_s[half][lane] = o;
        }
        __syncthreads();
        if (valid && lane < OUT_C)
            out[node * OUT_C + lane] = part_s[half][lane] + part_s[half][64 + lane] + bo_s[lane];
        __syncthreads();
    }
}

extern "C" void kernel_launch(void* const* d_in, const int* in_sizes, int n_in,
                              void* d_out, int out_size, void* d_ws, size_t ws_size,
                              hipStream_t stream) {
    const float* x = (const float*)d_in[0];
    const unsigned int* edge = (const unsigned int*)d_in[1];
    const float* Wl0 = (const float*)d_in[2];
    const float* Wr0 = (const float*)d_in[3];
    const float* bl0 = (const float*)d_in[4];
    const float* Wl1 = (const float*)d_in[5];
    const float* Wr1 = (const float*)d_in[6];
    const float* bl1 = (const float*)d_in[7];
    const float* Wo = (const float*)d_in[8];
    const float* bo = (const float*)d_in[9];
    float* out = (float*)d_out;

    char* w = (char*)d_ws;
    auto alloc = [&](size_t bytes) {
        char* p = w;
        w += (bytes + 255) & ~(size_t)255;
        return p;
    };
    int* flag = (int*)alloc(256);
    int* deg = (int*)alloc((size_t)N_NODES * 4);
    int* csr_off = (int*)alloc((size_t)(N_NODES + 1) * 4);
    int* cursor = (int*)alloc((size_t)N_NODES * 4);
    int* bsum = (int*)alloc(256 * 4);
    int* csr_src = (int*)alloc((size_t)N_EDGES * 4);
    float* h0 = (float*)alloc((size_t)N_NODES * HID_C * 4);

    hipMemsetAsync(deg, 0, (size_t)N_NODES * 4, stream);
    detect_i64_kernel<<<1, 64, 0, stream>>>(edge, flag);
    hist_kernel<<<1024, 256, 0, stream>>>(edge, flag, deg);
    const int NB = (N_NODES + 1023) / 1024;  // 98
    scan_block_kernel<<<NB, 1024, 0, stream>>>(deg, csr_off, bsum);
    scan_top_kernel<<<1, 128, 0, stream>>>(bsum, NB);
    add_off_kernel<<<391, 256, 0, stream>>>(csr_off, bsum, cursor);
    fill_kernel<<<1024, 256, 0, stream>>>(edge, flag, cursor, csr_src);

    const int NODE_BLOCKS = (N_NODES + 63) / 64;  // 1563
    layer0_kernel<<<NODE_BLOCKS, 256, 0, stream>>>(x, csr_off, csr_src, Wl0, Wr0, bl0, h0);
    layer1_kernel<<<NODE_BLOCKS, 256, 0, stream>>>(h0, csr_off, csr_src, Wl1, Wr1, bl1, Wo, bo,
                                                   out);
}

// Round 2
// 408.620 us; speedup vs baseline: 5.4979x; 5.4979x over previous
//
#include <hip/hip_runtime.h>

#define N_NODES 100000
#define N_EDGES 1250000
#define IN_C 64
#define HID_C 128
#define OUT_C 64

typedef __attribute__((ext_vector_type(8))) short short8;
typedef __attribute__((ext_vector_type(4))) float f32x4;

__device__ __forceinline__ float bflo(unsigned u) { return __uint_as_float(u << 16); }
__device__ __forceinline__ float bfhi(unsigned u) { return __uint_as_float(u & 0xffff0000u); }
__device__ __forceinline__ unsigned short f2bf(float f) {
    unsigned u = __float_as_uint(f);
    return (unsigned short)((u + 0x7fffu + ((u >> 16) & 1u)) >> 16);
}

// ---------- edge dtype detection (int64 vs int32 on device) ----------
__global__ void detect_i64_kernel(const unsigned int* __restrict__ e, int* __restrict__ flag) {
    unsigned v = e[2 * threadIdx.x + 1];
    unsigned long long b = __ballot(v != 0u);
    if (threadIdx.x == 0) flag[0] = (b == 0ull) ? 1 : 0;
}

__global__ void hist_kernel(const unsigned int* __restrict__ e, const int* __restrict__ flag,
                            int* __restrict__ deg) {
    const bool i64 = flag[0] != 0;
    for (int i = blockIdx.x * blockDim.x + threadIdx.x; i < N_EDGES;
         i += gridDim.x * blockDim.x) {
        int d = i64 ? (int)e[2 * (N_EDGES + i)] : (int)e[N_EDGES + i];
        atomicAdd(&deg[d], 1);
    }
}

__global__ __launch_bounds__(1024) void scan_block_kernel(const int* __restrict__ deg,
                                                          int* __restrict__ excl,
                                                          int* __restrict__ bsum) {
    __shared__ int s[1024];
    int tid = threadIdx.x;
    int i = blockIdx.x * 1024 + tid;
    int v = (i < N_NODES) ? deg[i] : 0;
    s[tid] = v;
    __syncthreads();
    for (int off = 1; off < 1024; off <<= 1) {
        int t = (tid >= off) ? s[tid - off] : 0;
        __syncthreads();
        s[tid] += t;
        __syncthreads();
    }
    if (i < N_NODES) excl[i] = s[tid] - v;
    if (tid == 1023) bsum[blockIdx.x] = s[1023];
}

__global__ void scan_top_kernel(int* __restrict__ bsum, int nb) {
    __shared__ int s[128];
    int tid = threadIdx.x;
    int v = (tid < nb) ? bsum[tid] : 0;
    s[tid] = v;
    __syncthreads();
    for (int off = 1; off < 128; off <<= 1) {
        int t = (tid >= off) ? s[tid - off] : 0;
        __syncthreads();
        s[tid] += t;
        __syncthreads();
    }
    if (tid < nb) bsum[tid] = s[tid] - v;
}

__global__ void add_off_kernel(int* __restrict__ excl, const int* __restrict__ bsum,
                               int* __restrict__ cursor) {
    for (int i = blockIdx.x * blockDim.x + threadIdx.x; i < N_NODES;
         i += gridDim.x * blockDim.x) {
        int v = excl[i] + bsum[i >> 10];
        excl[i] = v;
        cursor[i] = v;
        if (i == 0) excl[N_NODES] = N_EDGES;
    }
}

__global__ void fill_kernel(const unsigned int* __restrict__ e, const int* __restrict__ flag,
                            int* __restrict__ cursor, int* __restrict__ csr_src) {
    const bool i64 = flag[0] != 0;
    for (int i = blockIdx.x * blockDim.x + threadIdx.x; i < N_EDGES;
         i += gridDim.x * blockDim.x) {
        int sv = i64 ? (int)e[2 * i] : (int)e[i];
        int dv = i64 ? (int)e[2 * (N_EDGES + i)] : (int)e[N_EDGES + i];
        int pos = atomicAdd(&cursor[dv], 1);
        csr_src[pos] = sv;
    }
}

// ---------- fp32 -> bf16 converts ----------
__global__ void cvt_x_kernel(const float* __restrict__ x, unsigned short* __restrict__ xb) {
    int i = blockIdx.x * blockDim.x + threadIdx.x;
    if (i >= N_NODES * IN_C / 4) return;
    float4 v = ((const float4*)x)[i];
    unsigned lo = ((unsigned)f2bf(v.y) << 16) | f2bf(v.x);
    unsigned hi = ((unsigned)f2bf(v.w) << 16) | f2bf(v.z);
    ((uint2*)xb)[i] = make_uint2(lo, hi);
}

// wb segments: [0,8192) Wl0 | [8192,16384) Wr0 | [16384,32768) Wl1 | [32768,49152) Wr1 | [49152,57344) Wout
__global__ void cvt_w_kernel(const float* __restrict__ Wl0, const float* __restrict__ Wr0,
                             const float* __restrict__ Wl1, const float* __restrict__ Wr1,
                             const float* __restrict__ Wo, unsigned short* __restrict__ wb) {
    int i = blockIdx.x * blockDim.x + threadIdx.x;
    if (i >= 57344) return;
    float v;
    if (i < 8192) v = Wl0[i];
    else if (i < 16384) v = Wr0[i - 8192];
    else if (i < 32768) v = Wl1[i - 16384];
    else if (i < 49152) v = Wr1[i - 32768];
    else v = Wo[i - 49152];
    wb[i] = f2bf(v);
}

// ---------- aggregation: one wave per node, no LDS, max occupancy ----------
// x is [N x 64] bf16 (32 uints/row): 2 edge-slots x 32 channel-pair lanes.
__global__ __launch_bounds__(256) void agg0_kernel(
    const unsigned short* __restrict__ xb, const int* __restrict__ off,
    const int* __restrict__ csr_src, unsigned short* __restrict__ mean0b) {
    int wid = (blockIdx.x * 256 + threadIdx.x) >> 6;
    int lane = threadIdx.x & 63;
    if (wid >= N_NODES) return;
    int slot = lane >> 5, c2 = lane & 31;
    int beg = off[wid], end = off[wid + 1];
    const unsigned* base = (const unsigned*)xb;
    float s0 = 0.f, s1 = 0.f, t0 = 0.f, t1 = 0.f;
    int e = beg + slot;
    for (; e + 2 < end; e += 4) {
        int a = csr_src[e], b = csr_src[e + 2];
        unsigned ua = base[(size_t)a * 32 + c2];
        unsigned ub = base[(size_t)b * 32 + c2];
        s0 += bflo(ua); s1 += bfhi(ua);
        t0 += bflo(ub); t1 += bfhi(ub);
    }
    if (e < end) {
        unsigned u = base[(size_t)csr_src[e] * 32 + c2];
        s0 += bflo(u); s1 += bfhi(u);
    }
    s0 += t0; s1 += t1;
    s0 += __shfl_down(s0, 32);
    s1 += __shfl_down(s1, 32);
    if (slot == 0) {
        float invd = (end > beg) ? 1.f / (float)(end - beg) : 0.f;
        unsigned o = ((unsigned)f2bf(s1 * invd) << 16) | f2bf(s0 * invd);
        ((unsigned*)mean0b)[(size_t)wid * 32 + c2] = o;
    }
}

// h0b is [N x 128] bf16 (64 uints/row): 64 channel-pair lanes, 1 edge/iter, unroll 4.
__global__ __launch_bounds__(256) void agg1_kernel(
    const unsigned short* __restrict__ h0b, const int* __restrict__ off,
    const int* __restrict__ csr_src, unsigned short* __restrict__ mean1b) {
    int wid = (blockIdx.x * 256 + threadIdx.x) >> 6;
    int lane = threadIdx.x & 63;
    if (wid >= N_NODES) return;
    int beg = off[wid], end = off[wid + 1];
    const unsigned* base = (const unsigned*)h0b;
    float s0 = 0.f, s1 = 0.f;
    int e = beg;
    for (; e + 4 <= end; e += 4) {
        int a = csr_src[e], b = csr_src[e + 1], c = csr_src[e + 2], d = csr_src[e + 3];
        unsigned ua = base[(size_t)a * 64 + lane];
        unsigned ub = base[(size_t)b * 64 + lane];
        unsigned uc = base[(size_t)c * 64 + lane];
        unsigned ud = base[(size_t)d * 64 + lane];
        s0 += (bflo(ua) + bflo(ub)) + (bflo(uc) + bflo(ud));
        s1 += (bfhi(ua) + bfhi(ub)) + (bfhi(uc) + bfhi(ud));
    }
    for (; e < end; ++e) {
        unsigned u = base[(size_t)csr_src[e] * 64 + lane];
        s0 += bflo(u); s1 += bfhi(u);
    }
    float invd = (end > beg) ? 1.f / (float)(end - beg) : 0.f;
    unsigned o = ((unsigned)f2bf(s1 * invd) << 16) | f2bf(s0 * invd);
    ((unsigned*)mean1b)[(size_t)wid * 64 + lane] = o;
}

// ---------- gemm0: h0b = relu(mean0b @ Wl0 + b0 + xb @ Wr0), MFMA 16x16x32 ----------
// block = 512 thr = 8 waves; wave w = out-col tile [16w,16w+16); block = 16-node tile.
__global__ __launch_bounds__(512) void gemm0_kernel(
    const unsigned short* __restrict__ mean0b, const unsigned short* __restrict__ xb,
    const unsigned short* __restrict__ Wlb, const unsigned short* __restrict__ Wrb,
    const float* __restrict__ b0, unsigned short* __restrict__ h0b) {
    const int wave = threadIdx.x >> 6, lane = threadIdx.x & 63;
    const int r16 = lane & 15, q = lane >> 4;
    const int col = wave * 16 + r16;
    const int node0 = blockIdx.x * 16;

    short8 bl[2], br[2];
#pragma unroll
    for (int s = 0; s < 2; ++s) {
        const int k0 = s * 32 + q * 8;
#pragma unroll
        for (int j = 0; j < 8; ++j) {
            bl[s][j] = (short)Wlb[(k0 + j) * HID_C + col];
            br[s][j] = (short)Wrb[(k0 + j) * HID_C + col];
        }
    }
    f32x4 acc;
    { float b = b0[col]; acc[0] = b; acc[1] = b; acc[2] = b; acc[3] = b; }

    const size_t rowoff = (size_t)(node0 + r16) * IN_C;
#pragma unroll
    for (int s = 0; s < 2; ++s) {
        const int k0 = s * 32 + q * 8;
        short8 am = *(const short8*)(mean0b + rowoff + k0);
        short8 ax = *(const short8*)(xb + rowoff + k0);
        acc = __builtin_amdgcn_mfma_f32_16x16x32_bf16(am, bl[s], acc, 0, 0, 0);
        acc = __builtin_amdgcn_mfma_f32_16x16x32_bf16(ax, br[s], acc, 0, 0, 0);
    }
#pragma unroll
    for (int r = 0; r < 4; ++r) {
        int row = node0 + q * 4 + r;
        h0b[(size_t)row * HID_C + col] = f2bf(fmaxf(acc[r], 0.f));
    }
}

// ---- gemm1: out = relu(mean1b@Wl1 + b1 + h0b@Wr1) @ Wout + bout, fused via LDS ----
__global__ __launch_bounds__(512) void gemm1_kernel(
    const unsigned short* __restrict__ mean1b, const unsigned short* __restrict__ h0b,
    const unsigned short* __restrict__ Wlb, const unsigned short* __restrict__ Wrb,
    const unsigned short* __restrict__ Wob, const float* __restrict__ b1,
    const float* __restrict__ bo, float* __restrict__ out) {
    __shared__ unsigned short h1s[16 * HID_C];  // 4KB, XOR-swizzled by row
    const int wave = threadIdx.x >> 6, lane = threadIdx.x & 63;
    const int r16 = lane & 15, q = lane >> 4;
    const int col = wave * 16 + r16;
    const int node0 = blockIdx.x * 16;

    short8 bw0[4], bw1[4], wo[4];
#pragma unroll
    for (int s = 0; s < 4; ++s) {
        const int k0 = s * 32 + q * 8;
#pragma unroll
        for (int j = 0; j < 8; ++j) {
            bw0[s][j] = (short)Wlb[(k0 + j) * HID_C + col];
            bw1[s][j] = (short)Wrb[(k0 + j) * HID_C + col];
        }
    }
    if (wave < 4) {
#pragma unroll
        for (int s = 0; s < 4; ++s) {
            const int k0 = s * 32 + q * 8;
#pragma unroll
            for (int j = 0; j < 8; ++j) wo[s][j] = (short)Wob[(k0 + j) * OUT_C + col];
        }
    }

    f32x4 acc;
    { float b = b1[col]; acc[0] = b; acc[1] = b; acc[2] = b; acc[3] = b; }

    const size_t rowoff = (size_t)(node0 + r16) * HID_C;
#pragma unroll
    for (int s = 0; s < 4; ++s) {
        const int k0 = s * 32 + q * 8;
        short8 am = *(const short8*)(mean1b + rowoff + k0);
        short8 ah = *(const short8*)(h0b + rowoff + k0);
        acc = __builtin_amdgcn_mfma_f32_16x16x32_bf16(am, bw0[s], acc, 0, 0, 0);
        acc = __builtin_amdgcn_mfma_f32_16x16x32_bf16(ah, bw1[s], acc, 0, 0, 0);
    }

    // h1 -> LDS (bf16, swizzled): byte = (row*256 + col*2) ^ ((row&7)<<4)
#pragma unroll
    for (int r = 0; r < 4; ++r) {
        int row = q * 4 + r;
        int off = (row * 256 + col * 2) ^ ((row & 7) << 4);
        *(unsigned short*)((char*)h1s + off) = f2bf(fmaxf(acc[r], 0.f));
    }
    __syncthreads();

    if (wave < 4) {
        f32x4 oa;
        { float b = bo[col]; oa[0] = b; oa[1] = b; oa[2] = b; oa[3] = b; }
#pragma unroll
        for (int s = 0; s < 4; ++s) {
            int off = (r16 * 256 + (s * 32 + q * 8) * 2) ^ ((r16 & 7) << 4);
            short8 a = *(const short8*)((const char*)h1s + off);
            oa = __builtin_amdgcn_mfma_f32_16x16x32_bf16(a, wo[s], oa, 0, 0, 0);
        }
#pragma unroll
        for (int r = 0; r < 4; ++r) {
            int row = node0 + q * 4 + r;
            out[(size_t)row * OUT_C + col] = oa[r];
        }
    }
}

extern "C" void kernel_launch(void* const* d_in, const int* in_sizes, int n_in,
                              void* d_out, int out_size, void* d_ws, size_t ws_size,
                              hipStream_t stream) {
    const float* x = (const float*)d_in[0];
    const unsigned int* edge = (const unsigned int*)d_in[1];
    const float* Wl0 = (const float*)d_in[2];
    const float* Wr0 = (const float*)d_in[3];
    const float* bl0 = (const float*)d_in[4];
    const float* Wl1 = (const float*)d_in[5];
    const float* Wr1 = (const float*)d_in[6];
    const float* bl1 = (const float*)d_in[7];
    const float* Wo = (const float*)d_in[8];
    const float* bo = (const float*)d_in[9];
    float* out = (float*)d_out;

    char* w = (char*)d_ws;
    auto alloc = [&](size_t bytes) {
        char* p = w;
        w += (bytes + 255) & ~(size_t)255;
        return p;
    };
    int* flag = (int*)alloc(256);
    int* deg = (int*)alloc((size_t)N_NODES * 4);
    int* csr_off = (int*)alloc((size_t)(N_NODES + 1) * 4);
    int* cursor = (int*)alloc((size_t)N_NODES * 4);
    int* bsum = (int*)alloc(256 * 4);
    int* csr_src = (int*)alloc((size_t)N_EDGES * 4);
    unsigned short* xb = (unsigned short*)alloc((size_t)N_NODES * IN_C * 2);
    unsigned short* mean0b = (unsigned short*)alloc((size_t)N_NODES * IN_C * 2);
    unsigned short* h0b = (unsigned short*)alloc((size_t)N_NODES * HID_C * 2);
    unsigned short* mean1b = (unsigned short*)alloc((size_t)N_NODES * HID_C * 2);
    unsigned short* wb = (unsigned short*)alloc(57344 * 2);

    const unsigned short* Wl0b = wb;
    const unsigned short* Wr0b = wb + 8192;
    const unsigned short* Wl1b = wb + 16384;
    const unsigned short* Wr1b = wb + 32768;
    const unsigned short* Wob = wb + 49152;

    hipMemsetAsync(deg, 0, (size_t)N_NODES * 4, stream);
    detect_i64_kernel<<<1, 64, 0, stream>>>(edge, flag);
    hist_kernel<<<1024, 256, 0, stream>>>(edge, flag, deg);
    const int NB = (N_NODES + 1023) / 1024;  // 98
    scan_block_kernel<<<NB, 1024, 0, stream>>>(deg, csr_off, bsum);
    scan_top_kernel<<<1, 128, 0, stream>>>(bsum, NB);
    add_off_kernel<<<391, 256, 0, stream>>>(csr_off, bsum, cursor);
    fill_kernel<<<1024, 256, 0, stream>>>(edge, flag, cursor, csr_src);

    cvt_x_kernel<<<(N_NODES * IN_C / 4 + 255) / 256, 256, 0, stream>>>(x, xb);
    cvt_w_kernel<<<(57344 + 255) / 256, 256, 0, stream>>>(Wl0, Wr0, Wl1, Wr1, Wo, wb);

    const int AGG_BLOCKS = (N_NODES * 64 + 255) / 256;  // 25000
    const int TILE_BLOCKS = N_NODES / 16;               // 6250 (exact)

    agg0_kernel<<<AGG_BLOCKS, 256, 0, stream>>>(xb, csr_off, csr_src, mean0b);
    gemm0_kernel<<<TILE_BLOCKS, 512, 0, stream>>>(mean0b, xb, Wl0b, Wr0b, bl0, h0b);
    agg1_kernel<<<AGG_BLOCKS, 256, 0, stream>>>(h0b, csr_off, csr_src, mean1b);
    gemm1_kernel<<<TILE_BLOCKS, 512, 0, stream>>>(mean1b, h0b, Wl1b, Wr1b, Wob, bl1, bo, out);
}

// Round 3
// 375.238 us; speedup vs baseline: 5.9870x; 1.0890x over previous
//
#include <hip/hip_runtime.h>

#define N_NODES 100000
#define N_EDGES 1250000
#define IN_C 64
#define HID_C 128
#define OUT_C 64
#define NBUCK 98          // ceil(N_NODES / 1024)
#define PA_EPT 16
#define PA_EPB (256 * PA_EPT)  // 4096 edges per block
#define PA_BLOCKS ((N_EDGES + PA_EPB - 1) / PA_EPB)  // 306

typedef __attribute__((ext_vector_type(8))) short short8;
typedef __attribute__((ext_vector_type(4))) float f32x4;

__device__ __forceinline__ float bflo(unsigned u) { return __uint_as_float(u << 16); }
__device__ __forceinline__ float bfhi(unsigned u) { return __uint_as_float(u & 0xffff0000u); }
__device__ __forceinline__ unsigned short f2bf(float f) {
    unsigned u = __float_as_uint(f);
    return (unsigned short)((u + 0x7fffu + ((u >> 16) & 1u)) >> 16);
}

// ---------- edge dtype detection (int64 vs int32 on device) ----------
__global__ void detect_i64_kernel(const unsigned int* __restrict__ e, int* __restrict__ flag) {
    unsigned v = e[2 * threadIdx.x + 1];
    unsigned long long b = __ballot(v != 0u);
    if (threadIdx.x == 0) flag[0] = (b == 0ull) ? 1 : 0;
}

__global__ void hist_kernel(const unsigned int* __restrict__ e, const int* __restrict__ flag,
                            int* __restrict__ deg) {
    const bool i64 = flag[0] != 0;
    for (int i = blockIdx.x * blockDim.x + threadIdx.x; i < N_EDGES;
         i += gridDim.x * blockDim.x) {
        int d = i64 ? (int)e[2 * (N_EDGES + i)] : (int)e[N_EDGES + i];
        atomicAdd(&deg[d], 1);
    }
}

__global__ __launch_bounds__(1024) void scan_block_kernel(const int* __restrict__ deg,
                                                          int* __restrict__ excl,
                                                          int* __restrict__ bsum) {
    __shared__ int s[1024];
    int tid = threadIdx.x;
    int i = blockIdx.x * 1024 + tid;
    int v = (i < N_NODES) ? deg[i] : 0;
    s[tid] = v;
    __syncthreads();
    for (int off = 1; off < 1024; off <<= 1) {
        int t = (tid >= off) ? s[tid - off] : 0;
        __syncthreads();
        s[tid] += t;
        __syncthreads();
    }
    if (i < N_NODES) excl[i] = s[tid] - v;
    if (tid == 1023) bsum[blockIdx.x] = s[1023];
}

__global__ void scan_top_kernel(int* __restrict__ bsum, int nb) {
    __shared__ int s[128];
    int tid = threadIdx.x;
    int v = (tid < nb) ? bsum[tid] : 0;
    s[tid] = v;
    __syncthreads();
    for (int off = 1; off < 128; off <<= 1) {
        int t = (tid >= off) ? s[tid - off] : 0;
        __syncthreads();
        s[tid] += t;
        __syncthreads();
    }
    if (tid < nb) bsum[tid] = s[tid] - v;
}

__global__ void add_off_kernel(int* __restrict__ excl, const int* __restrict__ bsum,
                               int* __restrict__ cursor, int* __restrict__ bucketCursor) {
    for (int i = blockIdx.x * blockDim.x + threadIdx.x; i < N_NODES;
         i += gridDim.x * blockDim.x) {
        int v = excl[i] + bsum[i >> 10];
        excl[i] = v;
        cursor[i] = v;
        if ((i & 1023) == 0) bucketCursor[i >> 10] = v;
        if (i == 0) excl[N_NODES] = N_EDGES;
    }
}

// ---------- CSR build pass A: partition edges into 1024-node buckets ----------
// Bucket b's region in pairs[] is [csr_off[b<<10], csr_off[(b+1)<<10]) — same
// space as the final CSR, so pass B's scatter stays inside an L2-resident window.
__global__ __launch_bounds__(256) void partA_kernel(const unsigned int* __restrict__ e,
                                                    const int* __restrict__ flag,
                                                    int* __restrict__ bucketCursor,
                                                    uint2* __restrict__ pairs) {
    __shared__ int cnt[NBUCK];
    __shared__ int base[NBUCK];
    const bool i64 = flag[0] != 0;
    for (int t = threadIdx.x; t < NBUCK; t += 256) cnt[t] = 0;
    __syncthreads();
    const int e0 = blockIdx.x * PA_EPB;
    unsigned s[PA_EPT], d[PA_EPT];
    int rank[PA_EPT];
#pragma unroll
    for (int j = 0; j < PA_EPT; ++j) {
        int i = e0 + j * 256 + threadIdx.x;
        if (i < N_EDGES) {
            s[j] = i64 ? e[2 * i] : e[i];
            d[j] = i64 ? e[2 * (N_EDGES + i)] : e[N_EDGES + i];
            rank[j] = atomicAdd(&cnt[d[j] >> 10], 1);
        }
    }
    __syncthreads();
    for (int t = threadIdx.x; t < NBUCK; t += 256)
        base[t] = atomicAdd(&bucketCursor[t], cnt[t]);
    __syncthreads();
#pragma unroll
    for (int j = 0; j < PA_EPT; ++j) {
        int i = e0 + j * 256 + threadIdx.x;
        if (i < N_EDGES) pairs[base[d[j] >> 10] + rank[j]] = make_uint2(s[j], d[j]);
    }
}

// ---------- CSR build pass B: scatter within L2-resident bucket windows ----------
__global__ void partB_kernel(const uint2* __restrict__ pairs, int* __restrict__ cursor,
                             int* __restrict__ csr_src) {
    int i = blockIdx.x * blockDim.x + threadIdx.x;
    if (i >= N_EDGES) return;
    uint2 p = pairs[i];
    int pos = atomicAdd(&cursor[p.y], 1);
    csr_src[pos] = (int)p.x;
}

// ---------- fp32 -> bf16 converts ----------
__global__ void cvt_x_kernel(const float* __restrict__ x, unsigned short* __restrict__ xb) {
    int i = blockIdx.x * blockDim.x + threadIdx.x;
    if (i >= N_NODES * IN_C / 4) return;
    float4 v = ((const float4*)x)[i];
    unsigned lo = ((unsigned)f2bf(v.y) << 16) | f2bf(v.x);
    unsigned hi = ((unsigned)f2bf(v.w) << 16) | f2bf(v.z);
    ((uint2*)xb)[i] = make_uint2(lo, hi);
}

// wb segments: [0,8192) Wl0 | [8192,16384) Wr0 | [16384,32768) Wl1 | [32768,49152) Wr1 | [49152,57344) Wout
__global__ void cvt_w_kernel(const float* __restrict__ Wl0, const float* __restrict__ Wr0,
                             const float* __restrict__ Wl1, const float* __restrict__ Wr1,
                             const float* __restrict__ Wo, unsigned short* __restrict__ wb) {
    int i = blockIdx.x * blockDim.x + threadIdx.x;
    if (i >= 57344) return;
    float v;
    if (i < 8192) v = Wl0[i];
    else if (i < 16384) v = Wr0[i - 8192];
    else if (i < 32768) v = Wl1[i - 16384];
    else if (i < 49152) v = Wr1[i - 32768];
    else v = Wo[i - 49152];
    wb[i] = f2bf(v);
}

// ---------- aggregation: one wave per node, no LDS, max occupancy ----------
__global__ __launch_bounds__(256) void agg0_kernel(
    const unsigned short* __restrict__ xb, const int* __restrict__ off,
    const int* __restrict__ csr_src, unsigned short* __restrict__ mean0b) {
    int wid = (blockIdx.x * 256 + threadIdx.x) >> 6;
    int lane = threadIdx.x & 63;
    if (wid >= N_NODES) return;
    int slot = lane >> 5, c2 = lane & 31;
    int beg = off[wid], end = off[wid + 1];
    const unsigned* base = (const unsigned*)xb;
    float s0 = 0.f, s1 = 0.f, t0 = 0.f, t1 = 0.f;
    int e = beg + slot;
    for (; e + 2 < end; e += 4) {
        int a = csr_src[e], b = csr_src[e + 2];
        unsigned ua = base[(size_t)a * 32 + c2];
        unsigned ub = base[(size_t)b * 32 + c2];
        s0 += bflo(ua); s1 += bfhi(ua);
        t0 += bflo(ub); t1 += bfhi(ub);
    }
    if (e < end) {
        unsigned u = base[(size_t)csr_src[e] * 32 + c2];
        s0 += bflo(u); s1 += bfhi(u);
    }
    s0 += t0; s1 += t1;
    s0 += __shfl_down(s0, 32);
    s1 += __shfl_down(s1, 32);
    if (slot == 0) {
        float invd = (end > beg) ? 1.f / (float)(end - beg) : 0.f;
        unsigned o = ((unsigned)f2bf(s1 * invd) << 16) | f2bf(s0 * invd);
        ((unsigned*)mean0b)[(size_t)wid * 32 + c2] = o;
    }
}

__global__ __launch_bounds__(256) void agg1_kernel(
    const unsigned short* __restrict__ h0b, const int* __restrict__ off,
    const int* __restrict__ csr_src, unsigned short* __restrict__ mean1b) {
    int wid = (blockIdx.x * 256 + threadIdx.x) >> 6;
    int lane = threadIdx.x & 63;
    if (wid >= N_NODES) return;
    int beg = off[wid], end = off[wid + 1];
    const unsigned* base = (const unsigned*)h0b;
    float s0 = 0.f, s1 = 0.f;
    int e = beg;
    for (; e + 4 <= end; e += 4) {
        int a = csr_src[e], b = csr_src[e + 1], c = csr_src[e + 2], d = csr_src[e + 3];
        unsigned ua = base[(size_t)a * 64 + lane];
        unsigned ub = base[(size_t)b * 64 + lane];
        unsigned uc = base[(size_t)c * 64 + lane];
        unsigned ud = base[(size_t)d * 64 + lane];
        s0 += (bflo(ua) + bflo(ub)) + (bflo(uc) + bflo(ud));
        s1 += (bfhi(ua) + bfhi(ub)) + (bfhi(uc) + bfhi(ud));
    }
    for (; e < end; ++e) {
        unsigned u = base[(size_t)csr_src[e] * 64 + lane];
        s0 += bflo(u); s1 += bfhi(u);
    }
    float invd = (end > beg) ? 1.f / (float)(end - beg) : 0.f;
    unsigned o = ((unsigned)f2bf(s1 * invd) << 16) | f2bf(s0 * invd);
    ((unsigned*)mean1b)[(size_t)wid * 64 + lane] = o;
}

// ---------- gemm0: h0b = relu(mean0b @ Wl0 + b0 + xb @ Wr0), MFMA 16x16x32 ----------
__global__ __launch_bounds__(512) void gemm0_kernel(
    const unsigned short* __restrict__ mean0b, const unsigned short* __restrict__ xb,
    const unsigned short* __restrict__ Wlb, const unsigned short* __restrict__ Wrb,
    const float* __restrict__ b0, unsigned short* __restrict__ h0b) {
    const int wave = threadIdx.x >> 6, lane = threadIdx.x & 63;
    const int r16 = lane & 15, q = lane >> 4;
    const int col = wave * 16 + r16;
    const int node0 = blockIdx.x * 16;

    short8 bl[2], br[2];
#pragma unroll
    for (int s = 0; s < 2; ++s) {
        const int k0 = s * 32 + q * 8;
#pragma unroll
        for (int j = 0; j < 8; ++j) {
            bl[s][j] = (short)Wlb[(k0 + j) * HID_C + col];
            br[s][j] = (short)Wrb[(k0 + j) * HID_C + col];
        }
    }
    f32x4 acc;
    { float b = b0[col]; acc[0] = b; acc[1] = b; acc[2] = b; acc[3] = b; }

    const size_t rowoff = (size_t)(node0 + r16) * IN_C;
#pragma unroll
    for (int s = 0; s < 2; ++s) {
        const int k0 = s * 32 + q * 8;
        short8 am = *(const short8*)(mean0b + rowoff + k0);
        short8 ax = *(const short8*)(xb + rowoff + k0);
        acc = __builtin_amdgcn_mfma_f32_16x16x32_bf16(am, bl[s], acc, 0, 0, 0);
        acc = __builtin_amdgcn_mfma_f32_16x16x32_bf16(ax, br[s], acc, 0, 0, 0);
    }
#pragma unroll
    for (int r = 0; r < 4; ++r) {
        int row = node0 + q * 4 + r;
        h0b[(size_t)row * HID_C + col] = f2bf(fmaxf(acc[r], 0.f));
    }
}

// ---- gemm1: out = relu(mean1b@Wl1 + b1 + h0b@Wr1) @ Wout + bout, fused via LDS ----
__global__ __launch_bounds__(512) void gemm1_kernel(
    const unsigned short* __restrict__ mean1b, const unsigned short* __restrict__ h0b,
    const unsigned short* __restrict__ Wlb, const unsigned short* __restrict__ Wrb,
    const unsigned short* __restrict__ Wob, const float* __restrict__ b1,
    const float* __restrict__ bo, float* __restrict__ out) {
    __shared__ unsigned short h1s[16 * HID_C];  // 4KB, XOR-swizzled by row
    const int wave = threadIdx.x >> 6, lane = threadIdx.x & 63;
    const int r16 = lane & 15, q = lane >> 4;
    const int col = wave * 16 + r16;
    const int node0 = blockIdx.x * 16;

    short8 bw0[4], bw1[4], wo[4];
#pragma unroll
    for (int s = 0; s < 4; ++s) {
        const int k0 = s * 32 + q * 8;
#pragma unroll
        for (int j = 0; j < 8; ++j) {
            bw0[s][j] = (short)Wlb[(k0 + j) * HID_C + col];
            bw1[s][j] = (short)Wrb[(k0 + j) * HID_C + col];
        }
    }
    if (wave < 4) {
#pragma unroll
        for (int s = 0; s < 4; ++s) {
            const int k0 = s * 32 + q * 8;
#pragma unroll
            for (int j = 0; j < 8; ++j) wo[s][j] = (short)Wob[(k0 + j) * OUT_C + col];
        }
    }

    f32x4 acc;
    { float b = b1[col]; acc[0] = b; acc[1] = b; acc[2] = b; acc[3] = b; }

    const size_t rowoff = (size_t)(node0 + r16) * HID_C;
#pragma unroll
    for (int s = 0; s < 4; ++s) {
        const int k0 = s * 32 + q * 8;
        short8 am = *(const short8*)(mean1b + rowoff + k0);
        short8 ah = *(const short8*)(h0b + rowoff + k0);
        acc = __builtin_amdgcn_mfma_f32_16x16x32_bf16(am, bw0[s], acc, 0, 0, 0);
        acc = __builtin_amdgcn_mfma_f32_16x16x32_bf16(ah, bw1[s], acc, 0, 0, 0);
    }

#pragma unroll
    for (int r = 0; r < 4; ++r) {
        int row = q * 4 + r;
        int off = (row * 256 + col * 2) ^ ((row & 7) << 4);
        *(unsigned short*)((char*)h1s + off) = f2bf(fmaxf(acc[r], 0.f));
    }
    __syncthreads();

    if (wave < 4) {
        f32x4 oa;
        { float b = bo[col]; oa[0] = b; oa[1] = b; oa[2] = b; oa[3] = b; }
#pragma unroll
        for (int s = 0; s < 4; ++s) {
            int off = (r16 * 256 + (s * 32 + q * 8) * 2) ^ ((r16 & 7) << 4);
            short8 a = *(const short8*)((const char*)h1s + off);
            oa = __builtin_amdgcn_mfma_f32_16x16x32_bf16(a, wo[s], oa, 0, 0, 0);
        }
#pragma unroll
        for (int r = 0; r < 4; ++r) {
            int row = node0 + q * 4 + r;
            out[(size_t)row * OUT_C + col] = oa[r];
        }
    }
}

extern "C" void kernel_launch(void* const* d_in, const int* in_sizes, int n_in,
                              void* d_out, int out_size, void* d_ws, size_t ws_size,
                              hipStream_t stream) {
    const float* x = (const float*)d_in[0];
    const unsigned int* edge = (const unsigned int*)d_in[1];
    const float* Wl0 = (const float*)d_in[2];
    const float* Wr0 = (const float*)d_in[3];
    const float* bl0 = (const float*)d_in[4];
    const float* Wl1 = (const float*)d_in[5];
    const float* Wr1 = (const float*)d_in[6];
    const float* bl1 = (const float*)d_in[7];
    const float* Wo = (const float*)d_in[8];
    const float* bo = (const float*)d_in[9];
    float* out = (float*)d_out;

    char* w = (char*)d_ws;
    auto alloc = [&](size_t bytes) {
        char* p = w;
        w += (bytes + 255) & ~(size_t)255;
        return p;
    };
    int* flag = (int*)alloc(256);
    int* deg = (int*)alloc((size_t)N_NODES * 4);
    int* csr_off = (int*)alloc((size_t)(N_NODES + 1) * 4);
    int* cursor = (int*)alloc((size_t)N_NODES * 4);
    int* bucketCursor = (int*)alloc(NBUCK * 4);
    int* bsum = (int*)alloc(256 * 4);
    int* csr_src = (int*)alloc((size_t)N_EDGES * 4);
    uint2* pairs = (uint2*)alloc((size_t)N_EDGES * 8);
    unsigned short* xb = (unsigned short*)alloc((size_t)N_NODES * IN_C * 2);
    unsigned short* mean0b = (unsigned short*)alloc((size_t)N_NODES * IN_C * 2);
    unsigned short* h0b = (unsigned short*)alloc((size_t)N_NODES * HID_C * 2);
    unsigned short* mean1b = (unsigned short*)alloc((size_t)N_NODES * HID_C * 2);
    unsigned short* wb = (unsigned short*)alloc(57344 * 2);

    const unsigned short* Wl0b = wb;
    const unsigned short* Wr0b = wb + 8192;
    const unsigned short* Wl1b = wb + 16384;
    const unsigned short* Wr1b = wb + 32768;
    const unsigned short* Wob = wb + 49152;

    hipMemsetAsync(deg, 0, (size_t)N_NODES * 4, stream);
    detect_i64_kernel<<<1, 64, 0, stream>>>(edge, flag);
    hist_kernel<<<1024, 256, 0, stream>>>(edge, flag, deg);
    const int NB = (N_NODES + 1023) / 1024;  // 98
    scan_block_kernel<<<NB, 1024, 0, stream>>>(deg, csr_off, bsum);
    scan_top_kernel<<<1, 128, 0, stream>>>(bsum, NB);
    add_off_kernel<<<391, 256, 0, stream>>>(csr_off, bsum, cursor, bucketCursor);
    partA_kernel<<<PA_BLOCKS, 256, 0, stream>>>(edge, flag, bucketCursor, pairs);
    partB_kernel<<<(N_EDGES + 255) / 256, 256, 0, stream>>>(pairs, cursor, csr_src);

    cvt_x_kernel<<<(N_NODES * IN_C / 4 + 255) / 256, 256, 0, stream>>>(x, xb);
    cvt_w_kernel<<<(57344 + 255) / 256, 256, 0, stream>>>(Wl0, Wr0, Wl1, Wr1, Wo, wb);

    const int AGG_BLOCKS = (N_NODES * 64 + 255) / 256;  // 25000
    const int TILE_BLOCKS = N_NODES / 16;               // 6250 (exact)

    agg0_kernel<<<AGG_BLOCKS, 256, 0, stream>>>(xb, csr_off, csr_src, mean0b);
    gemm0_kernel<<<TILE_BLOCKS, 512, 0, stream>>>(mean0b, xb, Wl0b, Wr0b, bl0, h0b);
    agg1_kernel<<<AGG_BLOCKS, 256, 0, stream>>>(h0b, csr_off, csr_src, mean1b);
    gemm1_kernel<<<TILE_BLOCKS, 512, 0, stream>>>(mean1b, h0b, Wl1b, Wr1b, Wob, bl1, bo, out);
}

// Round 4
// 357.545 us; speedup vs baseline: 6.2833x; 1.0495x over previous
//
#include <hip/hip_runtime.h>

#define N_NODES 100000
#define N_EDGES 1250000
#define IN_C 64
#define HID_C 128
#define OUT_C 64
#define NBUCK 98          // ceil(N_NODES / 1024)
#define PA_EPT 16
#define PA_EPB (256 * PA_EPT)  // 4096 edges per block
#define PA_BLOCKS ((N_EDGES + PA_EPB - 1) / PA_EPB)  // 306
#define G_NR 8            // 16-node row-subtiles per gemm block (128 nodes)

typedef __attribute__((ext_vector_type(8))) short short8;
typedef __attribute__((ext_vector_type(4))) float f32x4;

__device__ __forceinline__ float bflo(unsigned u) { return __uint_as_float(u << 16); }
__device__ __forceinline__ float bfhi(unsigned u) { return __uint_as_float(u & 0xffff0000u); }
__device__ __forceinline__ unsigned short f2bf(float f) {
    unsigned u = __float_as_uint(f);
    return (unsigned short)((u + 0x7fffu + ((u >> 16) & 1u)) >> 16);
}

// ---------- edge dtype detection (int64 vs int32 on device) ----------
__global__ void detect_i64_kernel(const unsigned int* __restrict__ e, int* __restrict__ flag) {
    unsigned v = e[2 * threadIdx.x + 1];
    unsigned long long b = __ballot(v != 0u);
    if (threadIdx.x == 0) flag[0] = (b == 0ull) ? 1 : 0;
}

__global__ void hist_kernel(const unsigned int* __restrict__ e, const int* __restrict__ flag,
                            int* __restrict__ deg) {
    const bool i64 = flag[0] != 0;
    for (int i = blockIdx.x * blockDim.x + threadIdx.x; i < N_EDGES;
         i += gridDim.x * blockDim.x) {
        int d = i64 ? (int)e[2 * (N_EDGES + i)] : (int)e[N_EDGES + i];
        atomicAdd(&deg[d], 1);
    }
}

__global__ __launch_bounds__(1024) void scan_block_kernel(const int* __restrict__ deg,
                                                          int* __restrict__ excl,
                                                          int* __restrict__ bsum) {
    __shared__ int s[1024];
    int tid = threadIdx.x;
    int i = blockIdx.x * 1024 + tid;
    int v = (i < N_NODES) ? deg[i] : 0;
    s[tid] = v;
    __syncthreads();
    for (int off = 1; off < 1024; off <<= 1) {
        int t = (tid >= off) ? s[tid - off] : 0;
        __syncthreads();
        s[tid] += t;
        __syncthreads();
    }
    if (i < N_NODES) excl[i] = s[tid] - v;
    if (tid == 1023) bsum[blockIdx.x] = s[1023];
}

__global__ void scan_top_kernel(int* __restrict__ bsum, int nb) {
    __shared__ int s[128];
    int tid = threadIdx.x;
    int v = (tid < nb) ? bsum[tid] : 0;
    s[tid] = v;
    __syncthreads();
    for (int off = 1; off < 128; off <<= 1) {
        int t = (tid >= off) ? s[tid - off] : 0;
        __syncthreads();
        s[tid] += t;
        __syncthreads();
    }
    if (tid < nb) bsum[tid] = s[tid] - v;
}

__global__ void add_off_kernel(int* __restrict__ excl, const int* __restrict__ bsum,
                               int* __restrict__ cursor, int* __restrict__ bucketCursor) {
    for (int i = blockIdx.x * blockDim.x + threadIdx.x; i < N_NODES;
         i += gridDim.x * blockDim.x) {
        int v = excl[i] + bsum[i >> 10];
        excl[i] = v;
        cursor[i] = v;
        if ((i & 1023) == 0) bucketCursor[i >> 10] = v;
        if (i == 0) excl[N_NODES] = N_EDGES;
    }
}

// ---------- CSR build pass A: partition edges into 1024-node buckets ----------
__global__ __launch_bounds__(256) void partA_kernel(const unsigned int* __restrict__ e,
                                                    const int* __restrict__ flag,
                                                    int* __restrict__ bucketCursor,
                                                    uint2* __restrict__ pairs) {
    __shared__ int cnt[NBUCK];
    __shared__ int base[NBUCK];
    const bool i64 = flag[0] != 0;
    for (int t = threadIdx.x; t < NBUCK; t += 256) cnt[t] = 0;
    __syncthreads();
    const int e0 = blockIdx.x * PA_EPB;
    unsigned s[PA_EPT], d[PA_EPT];
    int rank[PA_EPT];
#pragma unroll
    for (int j = 0; j < PA_EPT; ++j) {
        int i = e0 + j * 256 + threadIdx.x;
        if (i < N_EDGES) {
            s[j] = i64 ? e[2 * i] : e[i];
            d[j] = i64 ? e[2 * (N_EDGES + i)] : e[N_EDGES + i];
            rank[j] = atomicAdd(&cnt[d[j] >> 10], 1);
        }
    }
    __syncthreads();
    for (int t = threadIdx.x; t < NBUCK; t += 256)
        base[t] = atomicAdd(&bucketCursor[t], cnt[t]);
    __syncthreads();
#pragma unroll
    for (int j = 0; j < PA_EPT; ++j) {
        int i = e0 + j * 256 + threadIdx.x;
        if (i < N_EDGES) pairs[base[d[j] >> 10] + rank[j]] = make_uint2(s[j], d[j]);
    }
}

// ---------- CSR build pass B: scatter within L2-resident bucket windows ----------
__global__ void partB_kernel(const uint2* __restrict__ pairs, int* __restrict__ cursor,
                             int* __restrict__ csr_src) {
    int i = blockIdx.x * blockDim.x + threadIdx.x;
    if (i >= N_EDGES) return;
    uint2 p = pairs[i];
    int pos = atomicAdd(&cursor[p.y], 1);
    csr_src[pos] = (int)p.x;
}

// ---------- fp32 -> bf16 converts ----------
__global__ void cvt_x_kernel(const float* __restrict__ x, unsigned short* __restrict__ xb) {
    int i = blockIdx.x * blockDim.x + threadIdx.x;
    if (i >= N_NODES * IN_C / 4) return;
    float4 v = ((const float4*)x)[i];
    unsigned lo = ((unsigned)f2bf(v.y) << 16) | f2bf(v.x);
    unsigned hi = ((unsigned)f2bf(v.w) << 16) | f2bf(v.z);
    ((uint2*)xb)[i] = make_uint2(lo, hi);
}

// Transposed bf16 weights WT[col][k] so a B-fragment is one contiguous short8.
// wb segments (shorts): [0,8192) Wl0T 128x64 | [8192,16384) Wr0T 128x64 |
// [16384,32768) Wl1T 128x128 | [32768,49152) Wr1T 128x128 | [49152,57344) WoT 64x128
__global__ void cvt_w_kernel(const float* __restrict__ Wl0, const float* __restrict__ Wr0,
                             const float* __restrict__ Wl1, const float* __restrict__ Wr1,
                             const float* __restrict__ Wo, unsigned short* __restrict__ wb) {
    int i = blockIdx.x * blockDim.x + threadIdx.x;
    if (i >= 57344) return;
    float v;
    if (i < 8192) {
        int col = i >> 6, k = i & 63;
        v = Wl0[k * HID_C + col];
    } else if (i < 16384) {
        int j = i - 8192;
        int col = j >> 6, k = j & 63;
        v = Wr0[k * HID_C + col];
    } else if (i < 32768) {
        int j = i - 16384;
        int col = j >> 7, k = j & 127;
        v = Wl1[k * HID_C + col];
    } else if (i < 49152) {
        int j = i - 32768;
        int col = j >> 7, k = j & 127;
        v = Wr1[k * HID_C + col];
    } else {
        int j = i - 49152;
        int col = j >> 7, k = j & 127;
        v = Wo[k * OUT_C + col];
    }
    wb[i] = f2bf(v);
}

// ---------- aggregation: one wave per node, no LDS, max occupancy ----------
__global__ __launch_bounds__(256) void agg0_kernel(
    const unsigned short* __restrict__ xb, const int* __restrict__ off,
    const int* __restrict__ csr_src, unsigned short* __restrict__ mean0b) {
    int wid = (blockIdx.x * 256 + threadIdx.x) >> 6;
    int lane = threadIdx.x & 63;
    if (wid >= N_NODES) return;
    int slot = lane >> 5, c2 = lane & 31;
    int beg = off[wid], end = off[wid + 1];
    const unsigned* base = (const unsigned*)xb;
    float s0 = 0.f, s1 = 0.f, t0 = 0.f, t1 = 0.f;
    int e = beg + slot;
    for (; e + 2 < end; e += 4) {
        int a = csr_src[e], b = csr_src[e + 2];
        unsigned ua = base[(size_t)a * 32 + c2];
        unsigned ub = base[(size_t)b * 32 + c2];
        s0 += bflo(ua); s1 += bfhi(ua);
        t0 += bflo(ub); t1 += bfhi(ub);
    }
    if (e < end) {
        unsigned u = base[(size_t)csr_src[e] * 32 + c2];
        s0 += bflo(u); s1 += bfhi(u);
    }
    s0 += t0; s1 += t1;
    s0 += __shfl_down(s0, 32);
    s1 += __shfl_down(s1, 32);
    if (slot == 0) {
        float invd = (end > beg) ? 1.f / (float)(end - beg) : 0.f;
        unsigned o = ((unsigned)f2bf(s1 * invd) << 16) | f2bf(s0 * invd);
        ((unsigned*)mean0b)[(size_t)wid * 32 + c2] = o;
    }
}

__global__ __launch_bounds__(256) void agg1_kernel(
    const unsigned short* __restrict__ h0b, const int* __restrict__ off,
    const int* __restrict__ csr_src, unsigned short* __restrict__ mean1b) {
    int wid = (blockIdx.x * 256 + threadIdx.x) >> 6;
    int lane = threadIdx.x & 63;
    if (wid >= N_NODES) return;
    int beg = off[wid], end = off[wid + 1];
    const unsigned* base = (const unsigned*)h0b;
    float s0 = 0.f, s1 = 0.f;
    int e = beg;
    for (; e + 4 <= end; e += 4) {
        int a = csr_src[e], b = csr_src[e + 1], c = csr_src[e + 2], d = csr_src[e + 3];
        unsigned ua = base[(size_t)a * 64 + lane];
        unsigned ub = base[(size_t)b * 64 + lane];
        unsigned uc = base[(size_t)c * 64 + lane];
        unsigned ud = base[(size_t)d * 64 + lane];
        s0 += (bflo(ua) + bflo(ub)) + (bflo(uc) + bflo(ud));
        s1 += (bfhi(ua) + bfhi(ub)) + (bfhi(uc) + bfhi(ud));
    }
    for (; e < end; ++e) {
        unsigned u = base[(size_t)csr_src[e] * 64 + lane];
        s0 += bflo(u); s1 += bfhi(u);
    }
    float invd = (end > beg) ? 1.f / (float)(end - beg) : 0.f;
    unsigned o = ((unsigned)f2bf(s1 * invd) << 16) | f2bf(s0 * invd);
    ((unsigned*)mean1b)[(size_t)wid * 64 + lane] = o;
}

// ---------- gemm0: h0b = relu(mean0b @ Wl0 + b0 + xb @ Wr0) ----------
// 8 waves x 16 cols = 128 out cols; G_NR row-subtiles of 16 nodes per block.
__global__ __launch_bounds__(512) void gemm0_kernel(
    const unsigned short* __restrict__ mean0b, const unsigned short* __restrict__ xb,
    const unsigned short* __restrict__ WlT, const unsigned short* __restrict__ WrT,
    const float* __restrict__ b0, unsigned short* __restrict__ h0b) {
    const int wave = threadIdx.x >> 6, lane = threadIdx.x & 63;
    const int r16 = lane & 15, q = lane >> 4;
    const int col = wave * 16 + r16;

    short8 bl[2], br[2];
#pragma unroll
    for (int s = 0; s < 2; ++s) {
        bl[s] = *(const short8*)(WlT + col * IN_C + s * 32 + q * 8);
        br[s] = *(const short8*)(WrT + col * IN_C + s * 32 + q * 8);
    }
    const float bias = b0[col];
    const int node0 = blockIdx.x * 16 * G_NR;

    for (int r = 0; r < G_NR; ++r) {
        const int rb = node0 + r * 16;
        if (rb >= N_NODES) break;
        f32x4 acc;
        acc[0] = bias; acc[1] = bias; acc[2] = bias; acc[3] = bias;
        const size_t rowoff = (size_t)(rb + r16) * IN_C;
#pragma unroll
        for (int s = 0; s < 2; ++s) {
            const int k0 = s * 32 + q * 8;
            short8 am = *(const short8*)(mean0b + rowoff + k0);
            short8 ax = *(const short8*)(xb + rowoff + k0);
            acc = __builtin_amdgcn_mfma_f32_16x16x32_bf16(am, bl[s], acc, 0, 0, 0);
            acc = __builtin_amdgcn_mfma_f32_16x16x32_bf16(ax, br[s], acc, 0, 0, 0);
        }
#pragma unroll
        for (int rr = 0; rr < 4; ++rr) {
            int row = rb + q * 4 + rr;
            h0b[(size_t)row * HID_C + col] = f2bf(fmaxf(acc[rr], 0.f));
        }
    }
}

// ---- gemm1: out = relu(mean1b@Wl1 + b1 + h0b@Wr1) @ Wout + bout ----
__global__ __launch_bounds__(512) void gemm1_kernel(
    const unsigned short* __restrict__ mean1b, const unsigned short* __restrict__ h0b,
    const unsigned short* __restrict__ WlT, const unsigned short* __restrict__ WrT,
    const unsigned short* __restrict__ WoT, const float* __restrict__ b1,
    const float* __restrict__ bo, float* __restrict__ out) {
    __shared__ unsigned short h1s[2][16 * HID_C];  // 8KB double-buffered, XOR-swizzled
    const int wave = threadIdx.x >> 6, lane = threadIdx.x & 63;
    const int r16 = lane & 15, q = lane >> 4;
    const int col = wave * 16 + r16;

    short8 bw0[4], bw1[4], wo[4];
    const int wcol = (wave < 4) ? col : 0;  // WoT has 64 cols
#pragma unroll
    for (int s = 0; s < 4; ++s) {
        bw0[s] = *(const short8*)(WlT + col * HID_C + s * 32 + q * 8);
        bw1[s] = *(const short8*)(WrT + col * HID_C + s * 32 + q * 8);
        wo[s] = *(const short8*)(WoT + wcol * HID_C + s * 32 + q * 8);
    }
    const float bias1 = b1[col];
    const float biaso = (wave < 4) ? bo[col] : 0.f;
    const int node0 = blockIdx.x * 16 * G_NR;

    for (int r = 0; r < G_NR; ++r) {
        const int rb = node0 + r * 16;
        if (rb >= N_NODES) break;
        f32x4 acc;
        acc[0] = bias1; acc[1] = bias1; acc[2] = bias1; acc[3] = bias1;
        const size_t rowoff = (size_t)(rb + r16) * HID_C;
#pragma unroll
        for (int s = 0; s < 4; ++s) {
            const int k0 = s * 32 + q * 8;
            short8 am = *(const short8*)(mean1b + rowoff + k0);
            short8 ah = *(const short8*)(h0b + rowoff + k0);
            acc = __builtin_amdgcn_mfma_f32_16x16x32_bf16(am, bw0[s], acc, 0, 0, 0);
            acc = __builtin_amdgcn_mfma_f32_16x16x32_bf16(ah, bw1[s], acc, 0, 0, 0);
        }
        unsigned short* hb = h1s[r & 1];
#pragma unroll
        for (int rr = 0; rr < 4; ++rr) {
            int row = q * 4 + rr;
            int off = (row * 256 + col * 2) ^ ((row & 7) << 4);
            *(unsigned short*)((char*)hb + off) = f2bf(fmaxf(acc[rr], 0.f));
        }
        __syncthreads();
        if (wave < 4) {
            f32x4 oa;
            oa[0] = biaso; oa[1] = biaso; oa[2] = biaso; oa[3] = biaso;
#pragma unroll
            for (int s = 0; s < 4; ++s) {
                int off = (r16 * 256 + (s * 32 + q * 8) * 2) ^ ((r16 & 7) << 4);
                short8 a = *(const short8*)((const char*)hb + off);
                oa = __builtin_amdgcn_mfma_f32_16x16x32_bf16(a, wo[s], oa, 0, 0, 0);
            }
#pragma unroll
            for (int rr = 0; rr < 4; ++rr) {
                int row = rb + q * 4 + rr;
                out[(size_t)row * OUT_C + col] = oa[rr];
            }
        }
    }
}

extern "C" void kernel_launch(void* const* d_in, const int* in_sizes, int n_in,
                              void* d_out, int out_size, void* d_ws, size_t ws_size,
                              hipStream_t stream) {
    const float* x = (const float*)d_in[0];
    const unsigned int* edge = (const unsigned int*)d_in[1];
    const float* Wl0 = (const float*)d_in[2];
    const float* Wr0 = (const float*)d_in[3];
    const float* bl0 = (const float*)d_in[4];
    const float* Wl1 = (const float*)d_in[5];
    const float* Wr1 = (const float*)d_in[6];
    const float* bl1 = (const float*)d_in[7];
    const float* Wo = (const float*)d_in[8];
    const float* bo = (const float*)d_in[9];
    float* out = (float*)d_out;

    char* w = (char*)d_ws;
    auto alloc = [&](size_t bytes) {
        char* p = w;
        w += (bytes + 255) & ~(size_t)255;
        return p;
    };
    int* flag = (int*)alloc(256);
    int* deg = (int*)alloc((size_t)N_NODES * 4);
    int* csr_off = (int*)alloc((size_t)(N_NODES + 1) * 4);
    int* cursor = (int*)alloc((size_t)N_NODES * 4);
    int* bucketCursor = (int*)alloc(NBUCK * 4);
    int* bsum = (int*)alloc(256 * 4);
    int* csr_src = (int*)alloc((size_t)N_EDGES * 4);
    uint2* pairs = (uint2*)alloc((size_t)N_EDGES * 8);
    unsigned short* xb = (unsigned short*)alloc((size_t)N_NODES * IN_C * 2);
    unsigned short* mean0b = (unsigned short*)alloc((size_t)N_NODES * IN_C * 2);
    unsigned short* h0b = (unsigned short*)alloc((size_t)N_NODES * HID_C * 2);
    unsigned short* mean1b = (unsigned short*)alloc((size_t)N_NODES * HID_C * 2);
    unsigned short* wb = (unsigned short*)alloc(57344 * 2);

    const unsigned short* Wl0T = wb;
    const unsigned short* Wr0T = wb + 8192;
    const unsigned short* Wl1T = wb + 16384;
    const unsigned short* Wr1T = wb + 32768;
    const unsigned short* WoT = wb + 49152;

    hipMemsetAsync(deg, 0, (size_t)N_NODES * 4, stream);
    detect_i64_kernel<<<1, 64, 0, stream>>>(edge, flag);
    hist_kernel<<<1024, 256, 0, stream>>>(edge, flag, deg);
    const int NB = (N_NODES + 1023) / 1024;  // 98
    scan_block_kernel<<<NB, 1024, 0, stream>>>(deg, csr_off, bsum);
    scan_top_kernel<<<1, 128, 0, stream>>>(bsum, NB);
    add_off_kernel<<<391, 256, 0, stream>>>(csr_off, bsum, cursor, bucketCursor);
    partA_kernel<<<PA_BLOCKS, 256, 0, stream>>>(edge, flag, bucketCursor, pairs);
    partB_kernel<<<(N_EDGES + 255) / 256, 256, 0, stream>>>(pairs, cursor, csr_src);

    cvt_x_kernel<<<(N_NODES * IN_C / 4 + 255) / 256, 256, 0, stream>>>(x, xb);
    cvt_w_kernel<<<(57344 + 255) / 256, 256, 0, stream>>>(Wl0, Wr0, Wl1, Wr1, Wo, wb);

    const int AGG_BLOCKS = (N_NODES * 64 + 255) / 256;          // 25000
    const int GEMM_BLOCKS = (N_NODES + 16 * G_NR - 1) / (16 * G_NR);  // 782

    agg0_kernel<<<AGG_BLOCKS, 256, 0, stream>>>(xb, csr_off, csr_src, mean0b);
    gemm0_kernel<<<GEMM_BLOCKS, 512, 0, stream>>>(mean0b, xb, Wl0T, Wr0T, bl0, h0b);
    agg1_kernel<<<AGG_BLOCKS, 256, 0, stream>>>(h0b, csr_off, csr_src, mean1b);
    gemm1_kernel<<<GEMM_BLOCKS, 512, 0, stream>>>(mean1b, h0b, Wl1T, Wr1T, WoT, bl1, bo, out);
}

// Round 5
// 357.192 us; speedup vs baseline: 6.2895x; 1.0010x over previous
//
#include <hip/hip_runtime.h>

#define N_NODES 100000
#define N_EDGES 1250000
#define IN_C 64
#define HID_C 128
#define OUT_C 64
#define NBUCK 98          // ceil(N_NODES / 1024)
#define PA_EPT 16
#define PA_EPB (256 * PA_EPT)  // 4096 edges per block
#define PA_BLOCKS ((N_EDGES + PA_EPB - 1) / PA_EPB)  // 306
#define G_NR 8            // 16-node row-subtiles per gemm block (128 nodes)

typedef __attribute__((ext_vector_type(8))) short short8;
typedef __attribute__((ext_vector_type(4))) float f32x4;

__device__ __forceinline__ float bflo(unsigned u) { return __uint_as_float(u << 16); }
__device__ __forceinline__ float bfhi(unsigned u) { return __uint_as_float(u & 0xffff0000u); }
__device__ __forceinline__ unsigned short f2bf(float f) {
    unsigned u = __float_as_uint(f);
    return (unsigned short)((u + 0x7fffu + ((u >> 16) & 1u)) >> 16);
}

// ---------- edge dtype detection (int64 vs int32 on device) ----------
__global__ void detect_i64_kernel(const unsigned int* __restrict__ e, int* __restrict__ flag) {
    unsigned v = e[2 * threadIdx.x + 1];
    unsigned long long b = __ballot(v != 0u);
    if (threadIdx.x == 0) flag[0] = (b == 0ull) ? 1 : 0;
}

__global__ void hist_kernel(const unsigned int* __restrict__ e, const int* __restrict__ flag,
                            int* __restrict__ deg) {
    const bool i64 = flag[0] != 0;
    for (int i = blockIdx.x * blockDim.x + threadIdx.x; i < N_EDGES;
         i += gridDim.x * blockDim.x) {
        int d = i64 ? (int)e[2 * (N_EDGES + i)] : (int)e[N_EDGES + i];
        atomicAdd(&deg[d], 1);
    }
}

__global__ __launch_bounds__(1024) void scan_block_kernel(const int* __restrict__ deg,
                                                          int* __restrict__ excl,
                                                          int* __restrict__ bsum) {
    __shared__ int s[1024];
    int tid = threadIdx.x;
    int i = blockIdx.x * 1024 + tid;
    int v = (i < N_NODES) ? deg[i] : 0;
    s[tid] = v;
    __syncthreads();
    for (int off = 1; off < 1024; off <<= 1) {
        int t = (tid >= off) ? s[tid - off] : 0;
        __syncthreads();
        s[tid] += t;
        __syncthreads();
    }
    if (i < N_NODES) excl[i] = s[tid] - v;
    if (tid == 1023) bsum[blockIdx.x] = s[1023];
}

__global__ void scan_top_kernel(int* __restrict__ bsum, int nb) {
    __shared__ int s[128];
    int tid = threadIdx.x;
    int v = (tid < nb) ? bsum[tid] : 0;
    s[tid] = v;
    __syncthreads();
    for (int off = 1; off < 128; off <<= 1) {
        int t = (tid >= off) ? s[tid - off] : 0;
        __syncthreads();
        s[tid] += t;
        __syncthreads();
    }
    if (tid < nb) bsum[tid] = s[tid] - v;
}

__global__ void add_off_kernel(int* __restrict__ excl, const int* __restrict__ bsum,
                               int* __restrict__ cursor, int* __restrict__ bucketCursor) {
    for (int i = blockIdx.x * blockDim.x + threadIdx.x; i < N_NODES;
         i += gridDim.x * blockDim.x) {
        int v = excl[i] + bsum[i >> 10];
        excl[i] = v;
        cursor[i] = v;
        if ((i & 1023) == 0) bucketCursor[i >> 10] = v;
        if (i == 0) excl[N_NODES] = N_EDGES;
    }
}

// ---------- CSR build pass A: partition edges into 1024-node buckets ----------
__global__ __launch_bounds__(256) void partA_kernel(const unsigned int* __restrict__ e,
                                                    const int* __restrict__ flag,
                                                    int* __restrict__ bucketCursor,
                                                    uint2* __restrict__ pairs) {
    __shared__ int cnt[NBUCK];
    __shared__ int base[NBUCK];
    const bool i64 = flag[0] != 0;
    for (int t = threadIdx.x; t < NBUCK; t += 256) cnt[t] = 0;
    __syncthreads();
    const int e0 = blockIdx.x * PA_EPB;
    unsigned s[PA_EPT], d[PA_EPT];
    int rank[PA_EPT];
#pragma unroll
    for (int j = 0; j < PA_EPT; ++j) {
        int i = e0 + j * 256 + threadIdx.x;
        if (i < N_EDGES) {
            s[j] = i64 ? e[2 * i] : e[i];
            d[j] = i64 ? e[2 * (N_EDGES + i)] : e[N_EDGES + i];
            rank[j] = atomicAdd(&cnt[d[j] >> 10], 1);
        }
    }
    __syncthreads();
    for (int t = threadIdx.x; t < NBUCK; t += 256)
        base[t] = atomicAdd(&bucketCursor[t], cnt[t]);
    __syncthreads();
#pragma unroll
    for (int j = 0; j < PA_EPT; ++j) {
        int i = e0 + j * 256 + threadIdx.x;
        if (i < N_EDGES) pairs[base[d[j] >> 10] + rank[j]] = make_uint2(s[j], d[j]);
    }
}

// ---------- CSR build pass B: scatter within L2-resident bucket windows ----------
__global__ void partB_kernel(const uint2* __restrict__ pairs, int* __restrict__ cursor,
                             int* __restrict__ csr_src) {
    int i = blockIdx.x * blockDim.x + threadIdx.x;
    if (i >= N_EDGES) return;
    uint2 p = pairs[i];
    int pos = atomicAdd(&cursor[p.y], 1);
    csr_src[pos] = (int)p.x;
}

// ---------- fp32 -> bf16 converts ----------
__global__ void cvt_x_kernel(const float* __restrict__ x, unsigned short* __restrict__ xb) {
    int i = blockIdx.x * blockDim.x + threadIdx.x;
    if (i >= N_NODES * IN_C / 4) return;
    float4 v = ((const float4*)x)[i];
    unsigned lo = ((unsigned)f2bf(v.y) << 16) | f2bf(v.x);
    unsigned hi = ((unsigned)f2bf(v.w) << 16) | f2bf(v.z);
    ((uint2*)xb)[i] = make_uint2(lo, hi);
}

// Transposed bf16 weights WT[col][k] so a B-fragment is one contiguous short8.
__global__ void cvt_w_kernel(const float* __restrict__ Wl0, const float* __restrict__ Wr0,
                             const float* __restrict__ Wl1, const float* __restrict__ Wr1,
                             const float* __restrict__ Wo, unsigned short* __restrict__ wb) {
    int i = blockIdx.x * blockDim.x + threadIdx.x;
    if (i >= 57344) return;
    float v;
    if (i < 8192) {
        int col = i >> 6, k = i & 63;
        v = Wl0[k * HID_C + col];
    } else if (i < 16384) {
        int j = i - 8192;
        int col = j >> 6, k = j & 63;
        v = Wr0[k * HID_C + col];
    } else if (i < 32768) {
        int j = i - 16384;
        int col = j >> 7, k = j & 127;
        v = Wl1[k * HID_C + col];
    } else if (i < 49152) {
        int j = i - 32768;
        int col = j >> 7, k = j & 127;
        v = Wr1[k * HID_C + col];
    } else {
        int j = i - 49152;
        int col = j >> 7, k = j & 127;
        v = Wo[k * OUT_C + col];
    }
    wb[i] = f2bf(v);
}

// ---------- aggregation: one wave per node, no LDS, max occupancy ----------
__global__ __launch_bounds__(256) void agg0_kernel(
    const unsigned short* __restrict__ xb, const int* __restrict__ off,
    const int* __restrict__ csr_src, unsigned short* __restrict__ mean0b) {
    int wid = (blockIdx.x * 256 + threadIdx.x) >> 6;
    int lane = threadIdx.x & 63;
    if (wid >= N_NODES) return;
    int slot = lane >> 5, c2 = lane & 31;
    int beg = off[wid], end = off[wid + 1];
    const unsigned* base = (const unsigned*)xb;
    float s0 = 0.f, s1 = 0.f, t0 = 0.f, t1 = 0.f;
    int e = beg + slot;
    for (; e + 2 < end; e += 4) {
        int a = csr_src[e], b = csr_src[e + 2];
        unsigned ua = base[(size_t)a * 32 + c2];
        unsigned ub = base[(size_t)b * 32 + c2];
        s0 += bflo(ua); s1 += bfhi(ua);
        t0 += bflo(ub); t1 += bfhi(ub);
    }
    if (e < end) {
        unsigned u = base[(size_t)csr_src[e] * 32 + c2];
        s0 += bflo(u); s1 += bfhi(u);
    }
    s0 += t0; s1 += t1;
    s0 += __shfl_down(s0, 32);
    s1 += __shfl_down(s1, 32);
    if (slot == 0) {
        float invd = (end > beg) ? 1.f / (float)(end - beg) : 0.f;
        unsigned o = ((unsigned)f2bf(s1 * invd) << 16) | f2bf(s0 * invd);
        ((unsigned*)mean0b)[(size_t)wid * 32 + c2] = o;
    }
}

__global__ __launch_bounds__(256) void agg1_kernel(
    const unsigned short* __restrict__ h0b, const int* __restrict__ off,
    const int* __restrict__ csr_src, unsigned short* __restrict__ mean1b) {
    int wid = (blockIdx.x * 256 + threadIdx.x) >> 6;
    int lane = threadIdx.x & 63;
    if (wid >= N_NODES) return;
    int beg = off[wid], end = off[wid + 1];
    const unsigned* base = (const unsigned*)h0b;
    float s0 = 0.f, s1 = 0.f;
    int e = beg;
    for (; e + 4 <= end; e += 4) {
        int a = csr_src[e], b = csr_src[e + 1], c = csr_src[e + 2], d = csr_src[e + 3];
        unsigned ua = base[(size_t)a * 64 + lane];
        unsigned ub = base[(size_t)b * 64 + lane];
        unsigned uc = base[(size_t)c * 64 + lane];
        unsigned ud = base[(size_t)d * 64 + lane];
        s0 += (bflo(ua) + bflo(ub)) + (bflo(uc) + bflo(ud));
        s1 += (bfhi(ua) + bfhi(ub)) + (bfhi(uc) + bfhi(ud));
    }
    for (; e < end; ++e) {
        unsigned u = base[(size_t)csr_src[e] * 64 + lane];
        s0 += bflo(u); s1 += bfhi(u);
    }
    float invd = (end > beg) ? 1.f / (float)(end - beg) : 0.f;
    unsigned o = ((unsigned)f2bf(s1 * invd) << 16) | f2bf(s0 * invd);
    ((unsigned*)mean1b)[(size_t)wid * 64 + lane] = o;
}

// ---------- gemm0: h0b = relu(mean0b @ Wl0 + b0 + xb @ Wr0) ----------
__global__ __launch_bounds__(512) void gemm0_kernel(
    const unsigned short* __restrict__ mean0b, const unsigned short* __restrict__ xb,
    const unsigned short* __restrict__ WlT, const unsigned short* __restrict__ WrT,
    const float* __restrict__ b0, unsigned short* __restrict__ h0b) {
    const int wave = threadIdx.x >> 6, lane = threadIdx.x & 63;
    const int r16 = lane & 15, q = lane >> 4;
    const int col = wave * 16 + r16;

    short8 bl[2], br[2];
#pragma unroll
    for (int s = 0; s < 2; ++s) {
        bl[s] = *(const short8*)(WlT + col * IN_C + s * 32 + q * 8);
        br[s] = *(const short8*)(WrT + col * IN_C + s * 32 + q * 8);
    }
    const float bias = b0[col];
    const int node0 = blockIdx.x * 16 * G_NR;

    for (int r = 0; r < G_NR; ++r) {
        const int rb = node0 + r * 16;
        if (rb >= N_NODES) break;
        f32x4 accA, accB;
        accA[0] = bias; accA[1] = bias; accA[2] = bias; accA[3] = bias;
        accB[0] = 0.f; accB[1] = 0.f; accB[2] = 0.f; accB[3] = 0.f;
        const size_t rowoff = (size_t)(rb + r16) * IN_C;
#pragma unroll
        for (int s = 0; s < 2; ++s) {
            const int k0 = s * 32 + q * 8;
            short8 am = *(const short8*)(mean0b + rowoff + k0);
            short8 ax = *(const short8*)(xb + rowoff + k0);
            accA = __builtin_amdgcn_mfma_f32_16x16x32_bf16(am, bl[s], accA, 0, 0, 0);
            accB = __builtin_amdgcn_mfma_f32_16x16x32_bf16(ax, br[s], accB, 0, 0, 0);
        }
#pragma unroll
        for (int rr = 0; rr < 4; ++rr) {
            int row = rb + q * 4 + rr;
            h0b[(size_t)row * HID_C + col] = f2bf(fmaxf(accA[rr] + accB[rr], 0.f));
        }
    }
}

// ---- gemm1: out = relu(mean1b@Wl1 + b1 + h0b@Wr1) @ Wout + bout ----
// Phase 1: all 128 rows of h1 -> 32KB swizzled LDS (8 independent subtiles).
// ONE barrier. Phase 2: 32 independent 16x16 projection tiles, 4 per wave.
__global__ __launch_bounds__(512) void gemm1_kernel(
    const unsigned short* __restrict__ mean1b, const unsigned short* __restrict__ h0b,
    const unsigned short* __restrict__ WlT, const unsigned short* __restrict__ WrT,
    const unsigned short* __restrict__ WoT, const float* __restrict__ b1,
    const float* __restrict__ bo, float* __restrict__ out) {
    __shared__ unsigned short h1s[128 * HID_C];  // 32KB, XOR-swizzled by row
    const int wave = threadIdx.x >> 6, lane = threadIdx.x & 63;
    const int r16 = lane & 15, q = lane >> 4;
    const int col = wave * 16 + r16;

    short8 bw0[4], bw1[4], wo[4];
    const int ct = wave & 3;               // phase-2 col-tile (out cols ct*16..+16)
    const int wcol = ct * 16 + r16;        // WoT col for this thread
#pragma unroll
    for (int s = 0; s < 4; ++s) {
        bw0[s] = *(const short8*)(WlT + col * HID_C + s * 32 + q * 8);
        bw1[s] = *(const short8*)(WrT + col * HID_C + s * 32 + q * 8);
        wo[s] = *(const short8*)(WoT + wcol * HID_C + s * 32 + q * 8);
    }
    const float bias1 = b1[col];
    const float biaso = bo[wcol];
    const int node0 = blockIdx.x * 16 * G_NR;

    // ---- phase 1: h1 tile -> LDS, no barriers between subtiles ----
#pragma unroll
    for (int r = 0; r < G_NR; ++r) {
        const int rb = node0 + r * 16;
        if (rb >= N_NODES) continue;
        f32x4 accA, accB;
        accA[0] = bias1; accA[1] = bias1; accA[2] = bias1; accA[3] = bias1;
        accB[0] = 0.f; accB[1] = 0.f; accB[2] = 0.f; accB[3] = 0.f;
        const size_t rowoff = (size_t)(rb + r16) * HID_C;
#pragma unroll
        for (int s = 0; s < 4; ++s) {
            const int k0 = s * 32 + q * 8;
            short8 am = *(const short8*)(mean1b + rowoff + k0);
            short8 ah = *(const short8*)(h0b + rowoff + k0);
            accA = __builtin_amdgcn_mfma_f32_16x16x32_bf16(am, bw0[s], accA, 0, 0, 0);
            accB = __builtin_amdgcn_mfma_f32_16x16x32_bf16(ah, bw1[s], accB, 0, 0, 0);
        }
#pragma unroll
        for (int rr = 0; rr < 4; ++rr) {
            int ar = r * 16 + q * 4 + rr;  // absolute row in tile
            int off = (ar * 256 + col * 2) ^ ((ar & 7) << 4);
            *(unsigned short*)((char*)h1s + off) = f2bf(fmaxf(accA[rr] + accB[rr], 0.f));
        }
    }
    __syncthreads();

    // ---- phase 2: out = h1 @ Wout + bo; wave handles 4 row-subtiles x 1 col-tile ----
    const int rs0 = (wave >> 2) * 4;  // row-subtiles rs0..rs0+3
#pragma unroll
    for (int t = 0; t < 4; ++t) {
        const int rs = rs0 + t;
        const int rb = node0 + rs * 16;
        if (rb >= N_NODES) continue;
        f32x4 oa;
        oa[0] = biaso; oa[1] = biaso; oa[2] = biaso; oa[3] = biaso;
#pragma unroll
        for (int s = 0; s < 4; ++s) {
            int ar = rs * 16 + r16;
            int off = (ar * 256 + (s * 32 + q * 8) * 2) ^ ((ar & 7) << 4);
            short8 a = *(const short8*)((const char*)h1s + off);
            oa = __builtin_amdgcn_mfma_f32_16x16x32_bf16(a, wo[s], oa, 0, 0, 0);
        }
#pragma unroll
        for (int rr = 0; rr < 4; ++rr) {
            int row = rb + q * 4 + rr;
            if (row < N_NODES) out[(size_t)row * OUT_C + wcol] = oa[rr];
        }
    }
}

extern "C" void kernel_launch(void* const* d_in, const int* in_sizes, int n_in,
                              void* d_out, int out_size, void* d_ws, size_t ws_size,
                              hipStream_t stream) {
    const float* x = (const float*)d_in[0];
    const unsigned int* edge = (const unsigned int*)d_in[1];
    const float* Wl0 = (const float*)d_in[2];
    const float* Wr0 = (const float*)d_in[3];
    const float* bl0 = (const float*)d_in[4];
    const float* Wl1 = (const float*)d_in[5];
    const float* Wr1 = (const float*)d_in[6];
    const float* bl1 = (const float*)d_in[7];
    const float* Wo = (const float*)d_in[8];
    const float* bo = (const float*)d_in[9];
    float* out = (float*)d_out;

    char* w = (char*)d_ws;
    auto alloc = [&](size_t bytes) {
        char* p = w;
        w += (bytes + 255) & ~(size_t)255;
        return p;
    };
    int* flag = (int*)alloc(256);
    int* deg = (int*)alloc((size_t)N_NODES * 4);
    int* csr_off = (int*)alloc((size_t)(N_NODES + 1) * 4);
    int* cursor = (int*)alloc((size_t)N_NODES * 4);
    int* bucketCursor = (int*)alloc(NBUCK * 4);
    int* bsum = (int*)alloc(256 * 4);
    int* csr_src = (int*)alloc((size_t)N_EDGES * 4);
    uint2* pairs = (uint2*)alloc((size_t)N_EDGES * 8);
    unsigned short* xb = (unsigned short*)alloc((size_t)N_NODES * IN_C * 2);
    unsigned short* mean0b = (unsigned short*)alloc((size_t)N_NODES * IN_C * 2);
    unsigned short* h0b = (unsigned short*)alloc((size_t)N_NODES * HID_C * 2);
    unsigned short* mean1b = (unsigned short*)alloc((size_t)N_NODES * HID_C * 2);
    unsigned short* wb = (unsigned short*)alloc(57344 * 2);

    const unsigned short* Wl0T = wb;
    const unsigned short* Wr0T = wb + 8192;
    const unsigned short* Wl1T = wb + 16384;
    const unsigned short* Wr1T = wb + 32768;
    const unsigned short* WoT = wb + 49152;

    hipMemsetAsync(deg, 0, (size_t)N_NODES * 4, stream);
    detect_i64_kernel<<<1, 64, 0, stream>>>(edge, flag);
    hist_kernel<<<1024, 256, 0, stream>>>(edge, flag, deg);
    const int NB = (N_NODES + 1023) / 1024;  // 98
    scan_block_kernel<<<NB, 1024, 0, stream>>>(deg, csr_off, bsum);
    scan_top_kernel<<<1, 128, 0, stream>>>(bsum, NB);
    add_off_kernel<<<391, 256, 0, stream>>>(csr_off, bsum, cursor, bucketCursor);
    partA_kernel<<<PA_BLOCKS, 256, 0, stream>>>(edge, flag, bucketCursor, pairs);
    partB_kernel<<<(N_EDGES + 255) / 256, 256, 0, stream>>>(pairs, cursor, csr_src);

    cvt_x_kernel<<<(N_NODES * IN_C / 4 + 255) / 256, 256, 0, stream>>>(x, xb);
    cvt_w_kernel<<<(57344 + 255) / 256, 256, 0, stream>>>(Wl0, Wr0, Wl1, Wr1, Wo, wb);

    const int AGG_BLOCKS = (N_NODES * 64 + 255) / 256;                // 25000
    const int GEMM_BLOCKS = (N_NODES + 16 * G_NR - 1) / (16 * G_NR);  // 782

    agg0_kernel<<<AGG_BLOCKS, 256, 0, stream>>>(xb, csr_off, csr_src, mean0b);
    gemm0_kernel<<<GEMM_BLOCKS, 512, 0, stream>>>(mean0b, xb, Wl0T, Wr0T, bl0, h0b);
    agg1_kernel<<<AGG_BLOCKS, 256, 0, stream>>>(h0b, csr_off, csr_src, mean1b);
    gemm1_kernel<<<GEMM_BLOCKS, 512, 0, stream>>>(mean1b, h0b, Wl1T, Wr1T, WoT, bl1, bo, out);
}